// Round 5
// baseline (8393.481 us; speedup 1.0000x reference)
//
#include <hip/hip_runtime.h>
#include <stdint.h>

#define B_ 64
#define T_ 512
#define D_ 1024
#define U_ 1024
#define G4_ 4096
#define M_ (B_ * T_)  // 32768

typedef unsigned short u16;
typedef float f32x4 __attribute__((ext_vector_type(4)));
typedef _Float16 f16x8 __attribute__((ext_vector_type(8)));
typedef unsigned short u16x4 __attribute__((ext_vector_type(4)));

__device__ __forceinline__ u16 f2h(float f) {
  union { _Float16 h; u16 u; } v; v.h = (_Float16)f; return v.u;
}
__device__ __forceinline__ float h2f(u16 u) {
  union { _Float16 h; u16 u; } v; v.u = u; return (float)v.h;
}
__device__ __forceinline__ float sigm(float x) { return 1.f / (1.f + __expf(-x)); }
__device__ __forceinline__ float tanhf_(float x) {
  x = fminf(12.f, fmaxf(-12.f, x));
  float e = __expf(2.f * x);
  return (e - 1.f) / (e + 1.f);
}

__device__ __forceinline__ void glds16(const void* g, void* l) {
  __builtin_amdgcn_global_load_lds(
      (const __attribute__((address_space(1))) uint32_t*)g,
      (__attribute__((address_space(3))) uint32_t*)l, 16, 0, 0);
}

// ---- generic row-strided stager (GEMM + fused fallback): swizzle (row&7)<<4
// applied to GLOBAL source (rule #21), LDS linear; read_frag applies same XOR.
template <int R>
__device__ __forceinline__ void stage_tile(const char* gbase, long gs, char* lds, int tid) {
  const int lane = tid & 63, wid = tid >> 6;
#pragma unroll
  for (int j = wid; j < R / 8; j += 4) {  // each wave-instr covers 1KB = 8 rows
    const int row = j * 8 + (lane >> 3);
    const int lg = ((lane & 7) * 16) ^ ((row & 7) << 4);
    glds16(gbase + (long)row * gs + lg, lds + j * 1024);
  }
}

__device__ __forceinline__ f16x8 read_frag(const char* lds, int row, int kbyte) {
  const int ph = row * 128 + (kbyte ^ ((row & 7) << 4));
  return *(const f16x8*)(lds + ph);
}

#define MFMA_(a, b, c) __builtin_amdgcn_mfma_f32_16x16x32_f16(a, b, c, 0, 0, 0)

// ---------------- prep kernels ----------------

__global__ __launch_bounds__(256) void cast_x_kernel(const float* __restrict__ x,
                                                     u16* __restrict__ xb) {
  const long n = (long)M_ * D_ / 4;
  for (long i = (long)blockIdx.x * blockDim.x + threadIdx.x; i < n;
       i += (long)gridDim.x * blockDim.x) {
    f32x4 v = ((const f32x4*)x)[i];
    u16x4 r;
#pragma unroll
    for (int j = 0; j < 4; ++j) r[j] = f2h(v[j]);
    ((u16x4*)xb)[i] = r;
  }
}

// Packed column p = ub*64 + g*16 + ui  <->  original col = g*1024 + ub*16 + ui.
__global__ __launch_bounds__(256) void pack_w_kernel(const float* __restrict__ Wf,
                                                     const float* __restrict__ Wb,
                                                     u16* __restrict__ wxT,
                                                     u16* __restrict__ whT) {
  const int idx = blockIdx.x * 256 + threadIdx.x;
  const int p = idx & 4095;
  const int kc = (idx >> 12) & 63;
  const int part = (idx >> 18) & 1;
  const int d = (idx >> 19) & 1;
  const float* W = d ? Wb : Wf;
  const int orig = ((p >> 4) & 3) * 1024 + ((p >> 6) << 4) + (p & 15);
  u16* dst = (part ? whT : wxT) + ((long)d * G4_ + p) * 1024 + kc * 16;
  const float* src = W + ((long)(part * 1024 + kc * 16)) * G4_ + orig;
#pragma unroll
  for (int j = 0; j < 16; ++j) dst[j] = f2h(src[(long)j * G4_]);
}

// ---------------- big x-projection GEMM (128x128 tile) ----------------
// Writes xp2 layout [d][t][ub(64)][b(64)][pl(64)] fp16, bias folded in.
__global__ __launch_bounds__(256) void gemm_xproj2(const u16* __restrict__ xbf,
                                                   const u16* __restrict__ wT,
                                                   const float* __restrict__ bF,
                                                   const float* __restrict__ bB,
                                                   u16* __restrict__ xp2) {
  __shared__ __align__(16) char smem[64 * 1024];
  const int tid = threadIdx.x, lane = tid & 63, wid = tid >> 6;
  const int wr = wid >> 1, wc = wid & 1;
  const int tm = blockIdx.x * 128, tn = blockIdx.y * 128, d = blockIdx.z;
  const char* Ag = (const char*)xbf + (long)tm * 2048;
  const char* Bg = (const char*)wT + ((long)d * G4_ + tn) * 2048;

  f32x4 acc[4][4];
#pragma unroll
  for (int mi = 0; mi < 4; ++mi)
#pragma unroll
    for (int ni = 0; ni < 4; ++ni)
#pragma unroll
      for (int v = 0; v < 4; ++v) acc[mi][ni][v] = 0.f;

  stage_tile<128>(Ag, 2048, smem, tid);
  stage_tile<128>(Bg, 2048, smem + 32768, tid);
  __syncthreads();
  const int rA = lane & 15, kb = (lane >> 4) * 16;

  for (int cc = 0; cc < 16; ++cc) {
    const int cur = cc & 1;
    char* Ac = smem + cur * 16384;
    char* Bc = smem + 32768 + cur * 16384;
    if (cc + 1 < 16) {
      stage_tile<128>(Ag + (cc + 1) * 128, 2048, smem + (cur ^ 1) * 16384, tid);
      stage_tile<128>(Bg + (cc + 1) * 128, 2048, smem + 32768 + (cur ^ 1) * 16384, tid);
    }
    f16x8 aF[4][2], bFr[4][2];
#pragma unroll
    for (int mi = 0; mi < 4; ++mi)
#pragma unroll
      for (int ks = 0; ks < 2; ++ks)
        aF[mi][ks] = read_frag(Ac, wr * 64 + mi * 16 + rA, kb + ks * 64);
#pragma unroll
    for (int ni = 0; ni < 4; ++ni)
#pragma unroll
      for (int ks = 0; ks < 2; ++ks)
        bFr[ni][ks] = read_frag(Bc, wc * 64 + ni * 16 + rA, kb + ks * 64);
#pragma unroll
    for (int mi = 0; mi < 4; ++mi)
#pragma unroll
      for (int ni = 0; ni < 4; ++ni)
#pragma unroll
        for (int ks = 0; ks < 2; ++ks)
          acc[mi][ni] = MFMA_(aF[mi][ks], bFr[ni][ks], acc[mi][ni]);
    __syncthreads();
  }

  const float* bias = d ? bB : bF;
#pragma unroll
  for (int ni = 0; ni < 4; ++ni) {
    const int p = tn + wc * 64 + ni * 16 + rA;
    const int orig = ((p >> 4) & 3) * 1024 + ((p >> 6) << 4) + (p & 15);
    const float bv = bias[orig];
    const int ub2 = p >> 6, pl = p & 63;
#pragma unroll
    for (int mi = 0; mi < 4; ++mi) {
      const int m0 = tm + wr * 64 + mi * 16 + (lane >> 4) * 4;
#pragma unroll
      for (int v = 0; v < 4; ++v) {
        const int m = m0 + v, b = m >> 9, t = m & 511;
        xp2[((((long)d * T_ + t) * 64 + ub2) * 64 + b) * 64 + pl] =
            f2h(acc[mi][ni][v] + bv);
      }
    }
  }
}

// ---------------- persistent recurrent kernel ----------------
// grid 128 blocks: bx -> d = bx&1, ub = bx>>1 (64 unit-blocks/dir).
// 512 threads (8 waves, 4M x 2N). Wh slice (64 packed cols x 1024 k, 128KB)
// resident in LDS for all 512 steps. Cross-block h exchange per step via a
// flag-array device barrier (agent-scope atomics, m20). h ping-pong in ws;
// c entirely in registers (2 floats/thread).
__global__ __launch_bounds__(512) void lstm_persist(
    const u16* __restrict__ whT, const u16* __restrict__ xp2,
    u16* __restrict__ hst, float* __restrict__ out,
    uint32_t* flags) {
  __shared__ __align__(16) char smem[147456];  // W 128K | zbuf 16K
  float* zbuf = (float*)(smem + 131072);
  const int tid = threadIdx.x, lane = tid & 63, wid = tid >> 6;
  const int bx = blockIdx.x, d = bx & 1, ub = bx >> 1;
  const int wm = wid >> 1, wn = wid & 1, rA = lane & 15, kq = lane >> 4;

  // ---- stage weights once (src-XOR swizzled, LDS linear; rule #21) ----
  {
    const char* wbase = (const char*)(whT + ((long)d * G4_ + ub * 64) * 1024);
#pragma unroll
    for (int q = 0; q < 16; ++q) {
      const int idx = wid * 16 + q;               // 128 x 1KB
      const int row = idx >> 1;                   // packed col 0..63
      const int jl = (idx & 1) * 1024 + lane * 16;
      glds16(wbase + (long)row * 2048 + (jl ^ ((row & 7) << 4)), smem + idx * 1024);
    }
  }

  // gate-phase mapping: thread -> (b = (tid>>4)*2 + j, ui = tid&15)
  const int ui_g = tid & 15, b0_g = (tid >> 4) * 2;
  const int u_g = ub * 16 + ui_g;
  float creg0 = 0.f, creg1 = 0.f;

  uint32_t* fl = flags + (long)d * 64 * 16;  // 64 padded slots per dir

  for (int s = 0; s < T_; ++s) {
    const int t = d ? (T_ - 1 - s) : s;

    // ---- barrier: wait until all 64 blocks of this dir finished step s-1 ----
    if (wid == 0) {
      int it = 0;
      while (true) {
        uint32_t v = __hip_atomic_load(fl + lane * 16, __ATOMIC_RELAXED,
                                       __HIP_MEMORY_SCOPE_AGENT);
        if (__all(v >= (uint32_t)s)) break;
        __builtin_amdgcn_s_sleep(1);
        if (++it > (1 << 16)) break;  // bailout: terminate rather than hang
      }
      (void)__hip_atomic_load(fl, __ATOMIC_ACQUIRE, __HIP_MEMORY_SCOPE_AGENT);
    }
    __syncthreads();  // also covers zbuf WAR vs previous step's gate reads

    // ---- prefetch xp gate values to regs (consumed after GEMM) ----
    const u16* xph = xp2 + ((((long)d * T_ + t) * 64 + ub) * 64) * 64;
    u16 xr0[4], xr1[4];
#pragma unroll
    for (int g = 0; g < 4; ++g) {
      xr0[g] = xph[(b0_g + 0) * 64 + g * 16 + ui_g];
      xr1[g] = xph[(b0_g + 1) * 64 + g * 16 + ui_g];
    }

    // ---- z = h_t @ Wh : M=64, N=64, K=1024; wave tile 16(M) x 32(N) ----
    const u16* hr = hst + (long)(s & 1) * 131072 + d * 65536;
    const u16* ha = hr + ((long)(wm * 16 + rA)) * 1024 + kq * 8;
    f32x4 acc0, acc1;
#pragma unroll
    for (int v = 0; v < 4; ++v) { acc0[v] = 0.f; acc1[v] = 0.f; }
#pragma unroll
    for (int kk = 0; kk < 32; ++kk) {
      const f16x8 aF = *(const f16x8*)(ha + kk * 32);
      const int kbyte = kk * 64 + kq * 16;
      const int r0 = wn * 32 + rA;
      const int r1 = wn * 32 + 16 + rA;
      const f16x8 bF0 = *(const f16x8*)(smem + r0 * 2048 + (kbyte ^ ((r0 & 7) << 4)));
      const f16x8 bF1 = *(const f16x8*)(smem + r1 * 2048 + (kbyte ^ ((r1 & 7) << 4)));
      acc0 = MFMA_(aF, bF0, acc0);
      acc1 = MFMA_(aF, bF1, acc1);
    }

    // ---- z -> LDS exchange ----
#pragma unroll
    for (int v = 0; v < 4; ++v) {
      const int row = wm * 16 + kq * 4 + v;
      zbuf[row * 64 + wn * 32 + rA] = acc0[v];
      zbuf[row * 64 + wn * 32 + 16 + rA] = acc1[v];
    }
    __syncthreads();

    // ---- gates, cell update, h/out writes ----
    u16* hw = hst + (long)((s + 1) & 1) * 131072 + d * 65536;
#pragma unroll
    for (int j = 0; j < 2; ++j) {
      const int b = b0_g + j;
      const u16* xr = j ? xr1 : xr0;
      const float zi = zbuf[b * 64 + ui_g] + h2f(xr[0]);
      const float zf = zbuf[b * 64 + 16 + ui_g] + h2f(xr[1]);
      const float zo = zbuf[b * 64 + 32 + ui_g] + h2f(xr[2]);
      const float zg = zbuf[b * 64 + 48 + ui_g] + h2f(xr[3]);
      const float c = j ? creg1 : creg0;
      const float i_ = sigm(zi), ff = sigm(zf), o_ = sigm(zo), g_ = tanhf_(zg);
      const float cn = ff * c + i_ * g_;
      const float hn = o_ * tanhf_(cn);
      if (j) creg1 = cn; else creg0 = cn;
      hw[b * 1024 + u_g] = f2h(hn);
      out[((long)b * T_ + t) * 2048 + d * 1024 + u_g] = hn;
    }

    __syncthreads();  // drains h stores (vmcnt(0) before s_barrier)
    if (tid == 0)
      __hip_atomic_store(fl + ub * 16, (uint32_t)(s + 1), __ATOMIC_RELEASE,
                         __HIP_MEMORY_SCOPE_AGENT);
  }
}

// ---------------- fused fallback (small workspace): r3-proven structure ------
__global__ __launch_bounds__(256) void lstm_step_fused(
    const u16* __restrict__ whT, const u16* __restrict__ wxT,
    const u16* __restrict__ xbf,
    const float* __restrict__ bF, const float* __restrict__ bB,
    const u16* __restrict__ h_read, u16* __restrict__ h_write,
    float* __restrict__ c_state, float* __restrict__ out, int s) {
  __shared__ __align__(16) char smem[32 * 1024];
  float* zbuf = (float*)smem;
  const int tid = threadIdx.x, lane = tid & 63, wid = tid >> 6;
  const int wr = wid >> 1, wc = wid & 1;
  const int ub = blockIdx.x, d = blockIdx.y;
  const int t = d ? (T_ - 1 - s) : s;
  const char* hA = (const char*)(h_read + (long)d * B_ * U_);
  const char* Bh = (const char*)(whT + ((long)d * G4_ + ub * 64) * 1024);
  const char* xA = (const char*)xbf + (long)t * (D_ * 2);
  const char* Bx = (const char*)(wxT + ((long)d * G4_ + ub * 64) * 1024);

  auto stage = [&](int cc, int buf) {
    char* Ad = smem + buf * 8192;
    char* Bd = smem + 16384 + buf * 8192;
    if (cc < 16) {
      stage_tile<64>(hA + cc * 128, U_ * 2, Ad, tid);
      stage_tile<64>(Bh + cc * 128, 1024 * 2, Bd, tid);
    } else {
      const int cx = cc - 16;
      stage_tile<64>(xA + cx * 128, (long)T_ * D_ * 2, Ad, tid);
      stage_tile<64>(Bx + cx * 128, 1024 * 2, Bd, tid);
    }
  };

  f32x4 acc[2][2];
#pragma unroll
  for (int mi = 0; mi < 2; ++mi)
#pragma unroll
    for (int ni = 0; ni < 2; ++ni)
#pragma unroll
      for (int v = 0; v < 4; ++v) acc[mi][ni][v] = 0.f;

  stage(0, 0);
  __syncthreads();
  const int rA = lane & 15, kb = (lane >> 4) * 16;

  for (int cc = 0; cc < 32; ++cc) {
    const int cur = cc & 1;
    char* Ac = smem + cur * 8192;
    char* Bc = smem + 16384 + cur * 8192;
    if (cc + 1 < 32) stage(cc + 1, cur ^ 1);
    f16x8 aF[2][2], bFr[2][2];
#pragma unroll
    for (int mi = 0; mi < 2; ++mi)
#pragma unroll
      for (int ks = 0; ks < 2; ++ks)
        aF[mi][ks] = read_frag(Ac, wr * 32 + mi * 16 + rA, kb + ks * 64);
#pragma unroll
    for (int ni = 0; ni < 2; ++ni)
#pragma unroll
      for (int ks = 0; ks < 2; ++ks)
        bFr[ni][ks] = read_frag(Bc, wc * 32 + ni * 16 + rA, kb + ks * 64);
#pragma unroll
    for (int mi = 0; mi < 2; ++mi)
#pragma unroll
      for (int ni = 0; ni < 2; ++ni)
#pragma unroll
        for (int ks = 0; ks < 2; ++ks)
          acc[mi][ni] = MFMA_(aF[mi][ks], bFr[ni][ks], acc[mi][ni]);
    __syncthreads();
  }

#pragma unroll
  for (int mi = 0; mi < 2; ++mi)
#pragma unroll
    for (int ni = 0; ni < 2; ++ni)
#pragma unroll
      for (int v = 0; v < 4; ++v) {
        const int row = wr * 32 + mi * 16 + (lane >> 4) * 4 + v;
        const int col = wc * 32 + ni * 16 + rA;
        zbuf[row * 64 + col] = acc[mi][ni][v];
      }
  __syncthreads();

  const int b = tid >> 2, u0 = (tid & 3) * 4;
  const float* bias = d ? bB : bF;
#pragma unroll
  for (int j = 0; j < 4; ++j) {
    const int ui = u0 + j, u = ub * 16 + ui;
    float zi = zbuf[b * 64 + ui] + bias[u];
    float zf = zbuf[b * 64 + 16 + ui] + bias[1024 + u];
    float zo = zbuf[b * 64 + 32 + ui] + bias[2048 + u];
    float zg = zbuf[b * 64 + 48 + ui] + bias[3072 + u];
    const long ci = (((long)d * B_ + b) << 10) + u;
    const float c = c_state[ci];
    const float i_ = sigm(zi), ff = sigm(zf), o_ = sigm(zo), g_ = tanhf_(zg);
    const float cn = ff * c + i_ * g_;
    const float hn = o_ * tanhf_(cn);
    c_state[ci] = cn;
    h_write[ci] = f2h(hn);
    out[(((long)b * T_ + t) << 11) + ((long)d << 10) + u] = hn;
  }
}

// ---------------- host launch ----------------

extern "C" void kernel_launch(void* const* d_in, const int* in_sizes, int n_in,
                              void* d_out, int out_size, void* d_ws, size_t ws_size,
                              hipStream_t stream) {
  const float* x = (const float*)d_in[0];
  const float* Wf = (const float*)d_in[1];
  const float* bfp = (const float*)d_in[2];
  const float* Wb = (const float*)d_in[3];
  const float* bbp = (const float*)d_in[4];
  float* out = (float*)d_out;
  char* ws = (char*)d_ws;

  size_t off = 0;
  auto alloc = [&](size_t bytes) {
    char* p = ws + off;
    off = (off + bytes + 255) & ~(size_t)255;
    return p;
  };
  u16* xbf = (u16*)alloc((size_t)M_ * D_ * 2);            // 64 MB
  u16* wxT = (u16*)alloc((size_t)2 * G4_ * 1024 * 2);     // 16 MB
  u16* whT = (u16*)alloc((size_t)2 * G4_ * 1024 * 2);     // 16 MB
  u16* hst = (u16*)alloc((size_t)2 * 2 * B_ * U_ * 2);    // ping-pong h
  float* cst = (float*)alloc((size_t)2 * B_ * U_ * 4);    // cell state (fallback)
  uint32_t* flags = (uint32_t*)alloc((size_t)2 * 64 * 16 * 4);  // barrier flags
  const size_t base_need = off;
  const size_t xproj_bytes = (size_t)2 * B_ * T_ * G4_ * 2;  // 512 MB
  const bool fused = (ws_size < base_need + xproj_bytes + 256);
  u16* xproj = fused ? nullptr : (u16*)alloc(xproj_bytes);

  hipMemsetAsync(hst, 0, (size_t)2 * 2 * B_ * U_ * 2, stream);
  hipMemsetAsync(flags, 0, (size_t)2 * 64 * 16 * 4, stream);

  cast_x_kernel<<<2048, 256, 0, stream>>>(x, xbf);
  pack_w_kernel<<<4096, 256, 0, stream>>>(Wf, Wb, wxT, whT);

  if (!fused) {
    dim3 gg(M_ / 128, G4_ / 128, 2);
    gemm_xproj2<<<gg, 256, 0, stream>>>(xbf, wxT, bfp, bbp, xproj);
    lstm_persist<<<128, 512, 0, stream>>>(whT, xproj, hst, out, flags);
  } else {
    hipMemsetAsync(cst, 0, (size_t)2 * B_ * U_ * 4, stream);
    for (int s = 0; s < T_; ++s) {
      const u16* hr = hst + (size_t)(s & 1) * 2 * B_ * U_;
      u16* hw = hst + (size_t)((s + 1) & 1) * 2 * B_ * U_;
      lstm_step_fused<<<dim3(64, 2), 256, 0, stream>>>(whT, wxT, xbf, bfp, bbp,
                                                       hr, hw, cst, out, s);
    }
  }
}

// Round 6
// 5697.692 us; speedup vs baseline: 1.4731x; 1.4731x over previous
//
#include <hip/hip_runtime.h>
#include <stdint.h>

#define B_ 64
#define T_ 512
#define D_ 1024
#define U_ 1024
#define G4_ 4096
#define M_ (B_ * T_)  // 32768

typedef unsigned short u16;
typedef float f32x4 __attribute__((ext_vector_type(4)));
typedef _Float16 f16x8 __attribute__((ext_vector_type(8)));
typedef unsigned short u16x4 __attribute__((ext_vector_type(4)));

__device__ __forceinline__ u16 f2h(float f) {
  union { _Float16 h; u16 u; } v; v.h = (_Float16)f; return v.u;
}
__device__ __forceinline__ float h2f(u16 u) {
  union { _Float16 h; u16 u; } v; v.u = u; return (float)v.h;
}
__device__ __forceinline__ float sigm(float x) { return 1.f / (1.f + __expf(-x)); }
__device__ __forceinline__ float tanhf_(float x) {
  x = fminf(12.f, fmaxf(-12.f, x));
  float e = __expf(2.f * x);
  return (e - 1.f) / (e + 1.f);
}

__device__ __forceinline__ void glds16(const void* g, void* l) {
  __builtin_amdgcn_global_load_lds(
      (const __attribute__((address_space(1))) uint32_t*)g,
      (__attribute__((address_space(3))) uint32_t*)l, 16, 0, 0);
}

// Coherent (LLC-direct) u32 store for cross-block h exchange — bypasses L1/L2
// so readers never need an invalidating acquire.
__device__ __forceinline__ void cohstore32(u16* p, uint32_t v) {
  __hip_atomic_store((__attribute__((address_space(1))) uint32_t*)(void*)p, v,
                     __ATOMIC_RELAXED, __HIP_MEMORY_SCOPE_AGENT);
}

// ---- generic row-strided stager (GEMM + fused fallback): swizzle (row&7)<<4
// applied to GLOBAL source (rule #21), LDS linear; read_frag applies same XOR.
template <int R>
__device__ __forceinline__ void stage_tile(const char* gbase, long gs, char* lds, int tid) {
  const int lane = tid & 63, wid = tid >> 6;
#pragma unroll
  for (int j = wid; j < R / 8; j += 4) {  // each wave-instr covers 1KB = 8 rows
    const int row = j * 8 + (lane >> 3);
    const int lg = ((lane & 7) * 16) ^ ((row & 7) << 4);
    glds16(gbase + (long)row * gs + lg, lds + j * 1024);
  }
}

__device__ __forceinline__ f16x8 read_frag(const char* lds, int row, int kbyte) {
  const int ph = row * 128 + (kbyte ^ ((row & 7) << 4));
  return *(const f16x8*)(lds + ph);
}

#define MFMA_(a, b, c) __builtin_amdgcn_mfma_f32_16x16x32_f16(a, b, c, 0, 0, 0)

// ---------------- prep kernels ----------------

__global__ __launch_bounds__(256) void cast_x_kernel(const float* __restrict__ x,
                                                     u16* __restrict__ xb) {
  const long n = (long)M_ * D_ / 4;
  for (long i = (long)blockIdx.x * blockDim.x + threadIdx.x; i < n;
       i += (long)gridDim.x * blockDim.x) {
    f32x4 v = ((const f32x4*)x)[i];
    u16x4 r;
#pragma unroll
    for (int j = 0; j < 4; ++j) r[j] = f2h(v[j]);
    ((u16x4*)xb)[i] = r;
  }
}

// Packed column p = ub*64 + g*16 + ui  <->  original col = g*1024 + ub*16 + ui.
__global__ __launch_bounds__(256) void pack_w_kernel(const float* __restrict__ Wf,
                                                     const float* __restrict__ Wb,
                                                     u16* __restrict__ wxT,
                                                     u16* __restrict__ whT) {
  const int idx = blockIdx.x * 256 + threadIdx.x;
  const int p = idx & 4095;
  const int kc = (idx >> 12) & 63;
  const int part = (idx >> 18) & 1;
  const int d = (idx >> 19) & 1;
  const float* W = d ? Wb : Wf;
  const int orig = ((p >> 4) & 3) * 1024 + ((p >> 6) << 4) + (p & 15);
  u16* dst = (part ? whT : wxT) + ((long)d * G4_ + p) * 1024 + kc * 16;
  const float* src = W + ((long)(part * 1024 + kc * 16)) * G4_ + orig;
#pragma unroll
  for (int j = 0; j < 16; ++j) dst[j] = f2h(src[(long)j * G4_]);
}

// ---------------- big x-projection GEMM (128x128 tile) ----------------
// Writes xp2 layout [d][t][ub(64)][b(64)][pl(64)] fp16, bias folded in.
__global__ __launch_bounds__(256) void gemm_xproj2(const u16* __restrict__ xbf,
                                                   const u16* __restrict__ wT,
                                                   const float* __restrict__ bF,
                                                   const float* __restrict__ bB,
                                                   u16* __restrict__ xp2) {
  __shared__ __align__(16) char smem[64 * 1024];
  const int tid = threadIdx.x, lane = tid & 63, wid = tid >> 6;
  const int wr = wid >> 1, wc = wid & 1;
  const int tm = blockIdx.x * 128, tn = blockIdx.y * 128, d = blockIdx.z;
  const char* Ag = (const char*)xbf + (long)tm * 2048;
  const char* Bg = (const char*)wT + ((long)d * G4_ + tn) * 2048;

  f32x4 acc[4][4];
#pragma unroll
  for (int mi = 0; mi < 4; ++mi)
#pragma unroll
    for (int ni = 0; ni < 4; ++ni)
#pragma unroll
      for (int v = 0; v < 4; ++v) acc[mi][ni][v] = 0.f;

  stage_tile<128>(Ag, 2048, smem, tid);
  stage_tile<128>(Bg, 2048, smem + 32768, tid);
  __syncthreads();
  const int rA = lane & 15, kb = (lane >> 4) * 16;

  for (int cc = 0; cc < 16; ++cc) {
    const int cur = cc & 1;
    char* Ac = smem + cur * 16384;
    char* Bc = smem + 32768 + cur * 16384;
    if (cc + 1 < 16) {
      stage_tile<128>(Ag + (cc + 1) * 128, 2048, smem + (cur ^ 1) * 16384, tid);
      stage_tile<128>(Bg + (cc + 1) * 128, 2048, smem + 32768 + (cur ^ 1) * 16384, tid);
    }
    f16x8 aF[4][2], bFr[4][2];
#pragma unroll
    for (int mi = 0; mi < 4; ++mi)
#pragma unroll
      for (int ks = 0; ks < 2; ++ks)
        aF[mi][ks] = read_frag(Ac, wr * 64 + mi * 16 + rA, kb + ks * 64);
#pragma unroll
    for (int ni = 0; ni < 4; ++ni)
#pragma unroll
      for (int ks = 0; ks < 2; ++ks)
        bFr[ni][ks] = read_frag(Bc, wc * 64 + ni * 16 + rA, kb + ks * 64);
#pragma unroll
    for (int mi = 0; mi < 4; ++mi)
#pragma unroll
      for (int ni = 0; ni < 4; ++ni)
#pragma unroll
        for (int ks = 0; ks < 2; ++ks)
          acc[mi][ni] = MFMA_(aF[mi][ks], bFr[ni][ks], acc[mi][ni]);
    __syncthreads();
  }

  const float* bias = d ? bB : bF;
#pragma unroll
  for (int ni = 0; ni < 4; ++ni) {
    const int p = tn + wc * 64 + ni * 16 + rA;
    const int orig = ((p >> 4) & 3) * 1024 + ((p >> 6) << 4) + (p & 15);
    const float bv = bias[orig];
    const int ub2 = p >> 6, pl = p & 63;
#pragma unroll
    for (int mi = 0; mi < 4; ++mi) {
      const int m0 = tm + wr * 64 + mi * 16 + (lane >> 4) * 4;
#pragma unroll
      for (int v = 0; v < 4; ++v) {
        const int m = m0 + v, b = m >> 9, t = m & 511;
        xp2[((((long)d * T_ + t) * 64 + ub2) * 64 + b) * 64 + pl] =
            f2h(acc[mi][ni][v] + bv);
      }
    }
  }
}

// ---------------- persistent recurrent kernel v2 ----------------
// 128 blocks (d, ub), 512 threads, 8 waves = 4 M-groups x 2 K-halves.
// Wh slice (64 cols x 1024 K) resident in LDS. Per step: flag-poll barrier,
// h read LLC-direct (sc0 sc1 dwordx4, 16 deep, ONE vmcnt wait), MFMA burst,
// zbuf K-combine, gates, coherent h store, flag release, out store last.
// No agent acquire anywhere -> L2 is never invalidated.
__global__ __launch_bounds__(512) void lstm_persist(
    const u16* __restrict__ whT, const u16* __restrict__ xp2,
    u16* __restrict__ hst, float* __restrict__ out, uint32_t* flags) {
  __shared__ __align__(16) char smem[147456];  // W 128K | zbuf 16K
  float* zbuf = (float*)(smem + 131072);
  const int tid = threadIdx.x, lane = tid & 63, wid = tid >> 6;
  const int bx = blockIdx.x, d = bx & 1, ub = bx >> 1;
  const int wm = wid & 3, kh = wid >> 2, rA = lane & 15, kq = lane >> 4;

  // ---- stage weights once (src-XOR swizzled, LDS linear; rule #21) ----
  {
    const char* wbase = (const char*)(whT + ((long)d * G4_ + ub * 64) * 1024);
#pragma unroll
    for (int q = 0; q < 16; ++q) {
      const int idx = wid * 16 + q;               // 128 x 1KB
      const int row = idx >> 1;                   // packed col 0..63
      const int jl = (idx & 1) * 1024 + lane * 16;
      glds16(wbase + (long)row * 2048 + (jl ^ ((row & 7) << 4)), smem + idx * 1024);
    }
  }

  // gate-phase mapping: thread -> b = tid>>3, u-pair up = tid&7 (2 adjacent u)
  const int b_g = tid >> 3, up_g = tid & 7;
  const int u_g = ub * 16 + up_g * 2;
  float creg0 = 0.f, creg1 = 0.f;
  uint32_t* fl = flags + (long)d * 64 * 16;

  for (int s = 0; s < T_; ++s) {
    const int t = d ? (T_ - 1 - s) : s;

    // ---- xp prefetch BEFORE the spin (overlaps barrier wait) ----
    const u16* xb = xp2 + ((((long)d * T_ + t) * 64 + ub) * 64 + b_g) * 64;
    uint32_t xr[4];
#pragma unroll
    for (int g = 0; g < 4; ++g)
      xr[g] = *(const uint32_t*)(xb + g * 16 + up_g * 2);

    // ---- barrier: all 64 blocks of this dir finished step s-1 ----
    if (wid == 0) {
      int it = 0;
      while (true) {
        uint32_t v = __hip_atomic_load(fl + lane * 16, __ATOMIC_RELAXED,
                                       __HIP_MEMORY_SCOPE_AGENT);
        if (__all(v >= (uint32_t)s)) break;
        __builtin_amdgcn_s_sleep(1);
        if (++it > (1 << 17)) break;  // bailout: terminate rather than hang
      }
    }
    __syncthreads();  // B1 (also step-data release within block + zbuf WAR)

    // ---- A-loads: 16 x global_load_dwordx4 sc0 sc1 (LLC-direct), one wait --
    const u16* hr = hst + (long)(s & 1) * 131072 + d * 65536;
    const char* abase =
        (const char*)(hr + ((long)(wm * 16 + rA)) * 1024) + kh * 1024 + kq * 16;
    f16x8 areg[16];
#define ALOAD(i)                                                        \
  asm volatile("global_load_dwordx4 %0, %1, off offset:%2 sc0 sc1"     \
               : "=v"(areg[i]) : "v"(abase), "n"(i * 64) : "memory")
    ALOAD(0); ALOAD(1); ALOAD(2); ALOAD(3);
    ALOAD(4); ALOAD(5); ALOAD(6); ALOAD(7);
    ALOAD(8); ALOAD(9); ALOAD(10); ALOAD(11);
    ALOAD(12); ALOAD(13); ALOAD(14); ALOAD(15);
#undef ALOAD
    asm volatile("s_waitcnt vmcnt(0)" ::: "memory");
    __builtin_amdgcn_sched_barrier(0);  // rule #18: no hoist past the wait

    // ---- MFMA burst: rows wm*16..+15, all 64 cols, K-half kh ----
    f32x4 acc[4];
#pragma unroll
    for (int ni = 0; ni < 4; ++ni)
#pragma unroll
      for (int v = 0; v < 4; ++v) acc[ni][v] = 0.f;
#pragma unroll
    for (int kk = 0; kk < 16; ++kk) {
      const int kbyte = kh * 1024 + kk * 64 + kq * 16;
#pragma unroll
      for (int ni = 0; ni < 4; ++ni) {
        const int pi = ni * 16 + rA;
        const f16x8 bF =
            *(const f16x8*)(smem + pi * 2048 + (kbyte ^ ((pi & 7) << 4)));
        acc[ni] = MFMA_(areg[kk], bF, acc[ni]);
      }
    }

    // ---- K-combine via zbuf: kh1 writes, kh0 adds ----
    if (kh == 1) {
#pragma unroll
      for (int ni = 0; ni < 4; ++ni)
#pragma unroll
        for (int v = 0; v < 4; ++v)
          zbuf[(wm * 16 + kq * 4 + v) * 64 + ni * 16 + rA] = acc[ni][v];
    }
    __syncthreads();  // B2
    if (kh == 0) {
#pragma unroll
      for (int ni = 0; ni < 4; ++ni)
#pragma unroll
        for (int v = 0; v < 4; ++v) {
          const int ix = (wm * 16 + kq * 4 + v) * 64 + ni * 16 + rA;
          zbuf[ix] += acc[ni][v];
        }
    }
    __syncthreads();  // B3

    // ---- gates: 2 adjacent units of one batch per thread ----
    const float* zb = zbuf + b_g * 64 + up_g * 2;
    const float zi0 = zb[0]  + h2f((u16)(xr[0] & 0xffff));
    const float zi1 = zb[1]  + h2f((u16)(xr[0] >> 16));
    const float zf0 = zb[16] + h2f((u16)(xr[1] & 0xffff));
    const float zf1 = zb[17] + h2f((u16)(xr[1] >> 16));
    const float zo0 = zb[32] + h2f((u16)(xr[2] & 0xffff));
    const float zo1 = zb[33] + h2f((u16)(xr[2] >> 16));
    const float zg0 = zb[48] + h2f((u16)(xr[3] & 0xffff));
    const float zg1 = zb[49] + h2f((u16)(xr[3] >> 16));
    const float cn0 = sigm(zf0) * creg0 + sigm(zi0) * tanhf_(zg0);
    const float cn1 = sigm(zf1) * creg1 + sigm(zi1) * tanhf_(zg1);
    const float hn0 = sigm(zo0) * tanhf_(cn0);
    const float hn1 = sigm(zo1) * tanhf_(cn1);
    creg0 = cn0; creg1 = cn1;

    // ---- coherent h store (to LLC), drain via B4's vmcnt(0), then flag ----
    u16* hw = hst + (long)((s + 1) & 1) * 131072 + d * 65536;
    cohstore32(hw + (long)b_g * 1024 + u_g,
               (uint32_t)f2h(hn0) | ((uint32_t)f2h(hn1) << 16));
    __syncthreads();  // B4: emits s_waitcnt vmcnt(0) before s_barrier
    if (tid == 0)
      __hip_atomic_store(fl + ub * 16, (uint32_t)(s + 1), __ATOMIC_RELEASE,
                         __HIP_MEMORY_SCOPE_AGENT);

    // ---- out store AFTER release (off the critical path) ----
    float2 o2; o2.x = hn0; o2.y = hn1;
    *(float2*)(out + ((long)b_g * T_ + t) * 2048 + d * 1024 + u_g) = o2;
  }
}

// ---------------- fused fallback (small workspace): r3-proven structure ------
__global__ __launch_bounds__(256) void lstm_step_fused(
    const u16* __restrict__ whT, const u16* __restrict__ wxT,
    const u16* __restrict__ xbf,
    const float* __restrict__ bF, const float* __restrict__ bB,
    const u16* __restrict__ h_read, u16* __restrict__ h_write,
    float* __restrict__ c_state, float* __restrict__ out, int s) {
  __shared__ __align__(16) char smem[32 * 1024];
  float* zbuf = (float*)smem;
  const int tid = threadIdx.x, lane = tid & 63, wid = tid >> 6;
  const int wr = wid >> 1, wc = wid & 1;
  const int ub = blockIdx.x, d = blockIdx.y;
  const int t = d ? (T_ - 1 - s) : s;
  const char* hA = (const char*)(h_read + (long)d * B_ * U_);
  const char* Bh = (const char*)(whT + ((long)d * G4_ + ub * 64) * 1024);
  const char* xA = (const char*)xbf + (long)t * (D_ * 2);
  const char* Bx = (const char*)(wxT + ((long)d * G4_ + ub * 64) * 1024);

  auto stage = [&](int cc, int buf) {
    char* Ad = smem + buf * 8192;
    char* Bd = smem + 16384 + buf * 8192;
    if (cc < 16) {
      stage_tile<64>(hA + cc * 128, U_ * 2, Ad, tid);
      stage_tile<64>(Bh + cc * 128, 1024 * 2, Bd, tid);
    } else {
      const int cx = cc - 16;
      stage_tile<64>(xA + cx * 128, (long)T_ * D_ * 2, Ad, tid);
      stage_tile<64>(Bx + cx * 128, 1024 * 2, Bd, tid);
    }
  };

  f32x4 acc[2][2];
#pragma unroll
  for (int mi = 0; mi < 2; ++mi)
#pragma unroll
    for (int ni = 0; ni < 2; ++ni)
#pragma unroll
      for (int v = 0; v < 4; ++v) acc[mi][ni][v] = 0.f;

  stage(0, 0);
  __syncthreads();
  const int rA = lane & 15, kb = (lane >> 4) * 16;

  for (int cc = 0; cc < 32; ++cc) {
    const int cur = cc & 1;
    char* Ac = smem + cur * 8192;
    char* Bc = smem + 16384 + cur * 8192;
    if (cc + 1 < 32) stage(cc + 1, cur ^ 1);
    f16x8 aF[2][2], bFr[2][2];
#pragma unroll
    for (int mi = 0; mi < 2; ++mi)
#pragma unroll
      for (int ks = 0; ks < 2; ++ks)
        aF[mi][ks] = read_frag(Ac, wr * 32 + mi * 16 + rA, kb + ks * 64);
#pragma unroll
    for (int ni = 0; ni < 2; ++ni)
#pragma unroll
      for (int ks = 0; ks < 2; ++ks)
        bFr[ni][ks] = read_frag(Bc, wc * 32 + ni * 16 + rA, kb + ks * 64);
#pragma unroll
    for (int mi = 0; mi < 2; ++mi)
#pragma unroll
      for (int ni = 0; ni < 2; ++ni)
#pragma unroll
        for (int ks = 0; ks < 2; ++ks)
          acc[mi][ni] = MFMA_(aF[mi][ks], bFr[ni][ks], acc[mi][ni]);
    __syncthreads();
  }

#pragma unroll
  for (int mi = 0; mi < 2; ++mi)
#pragma unroll
    for (int ni = 0; ni < 2; ++ni)
#pragma unroll
      for (int v = 0; v < 4; ++v) {
        const int row = wr * 32 + mi * 16 + (lane >> 4) * 4 + v;
        const int col = wc * 32 + ni * 16 + rA;
        zbuf[row * 64 + col] = acc[mi][ni][v];
      }
  __syncthreads();

  const int b = tid >> 2, u0 = (tid & 3) * 4;
  const float* bias = d ? bB : bF;
#pragma unroll
  for (int j = 0; j < 4; ++j) {
    const int ui = u0 + j, u = ub * 16 + ui;
    float zi = zbuf[b * 64 + ui] + bias[u];
    float zf = zbuf[b * 64 + 16 + ui] + bias[1024 + u];
    float zo = zbuf[b * 64 + 32 + ui] + bias[2048 + u];
    float zg = zbuf[b * 64 + 48 + ui] + bias[3072 + u];
    const long ci = (((long)d * B_ + b) << 10) + u;
    const float c = c_state[ci];
    const float i_ = sigm(zi), ff = sigm(zf), o_ = sigm(zo), g_ = tanhf_(zg);
    const float cn = ff * c + i_ * g_;
    const float hn = o_ * tanhf_(cn);
    c_state[ci] = cn;
    h_write[ci] = f2h(hn);
    out[(((long)b * T_ + t) << 11) + ((long)d << 10) + u] = hn;
  }
}

// ---------------- host launch ----------------

extern "C" void kernel_launch(void* const* d_in, const int* in_sizes, int n_in,
                              void* d_out, int out_size, void* d_ws, size_t ws_size,
                              hipStream_t stream) {
  const float* x = (const float*)d_in[0];
  const float* Wf = (const float*)d_in[1];
  const float* bfp = (const float*)d_in[2];
  const float* Wb = (const float*)d_in[3];
  const float* bbp = (const float*)d_in[4];
  float* out = (float*)d_out;
  char* ws = (char*)d_ws;

  size_t off = 0;
  auto alloc = [&](size_t bytes) {
    char* p = ws + off;
    off = (off + bytes + 255) & ~(size_t)255;
    return p;
  };
  u16* xbf = (u16*)alloc((size_t)M_ * D_ * 2);            // 64 MB
  u16* wxT = (u16*)alloc((size_t)2 * G4_ * 1024 * 2);     // 16 MB
  u16* whT = (u16*)alloc((size_t)2 * G4_ * 1024 * 2);     // 16 MB
  u16* hst = (u16*)alloc((size_t)2 * 2 * B_ * U_ * 2);    // ping-pong h
  float* cst = (float*)alloc((size_t)2 * B_ * U_ * 4);    // cell state (fallback)
  uint32_t* flags = (uint32_t*)alloc((size_t)2 * 64 * 16 * 4);  // barrier flags
  const size_t base_need = off;
  const size_t xproj_bytes = (size_t)2 * B_ * T_ * G4_ * 2;  // 512 MB
  const bool fused = (ws_size < base_need + xproj_bytes + 256);
  u16* xproj = fused ? nullptr : (u16*)alloc(xproj_bytes);

  hipMemsetAsync(hst, 0, (size_t)2 * 2 * B_ * U_ * 2, stream);
  hipMemsetAsync(flags, 0, (size_t)2 * 64 * 16 * 4, stream);

  cast_x_kernel<<<2048, 256, 0, stream>>>(x, xbf);
  pack_w_kernel<<<4096, 256, 0, stream>>>(Wf, Wb, wxT, whT);

  if (!fused) {
    dim3 gg(M_ / 128, G4_ / 128, 2);
    gemm_xproj2<<<gg, 256, 0, stream>>>(xbf, wxT, bfp, bbp, xproj);
    lstm_persist<<<128, 512, 0, stream>>>(whT, xproj, hst, out, flags);
  } else {
    hipMemsetAsync(cst, 0, (size_t)2 * B_ * U_ * 4, stream);
    for (int s = 0; s < T_; ++s) {
      const u16* hr = hst + (size_t)(s & 1) * 2 * B_ * U_;
      u16* hw = hst + (size_t)((s + 1) & 1) * 2 * B_ * U_;
      lstm_step_fused<<<dim3(64, 2), 256, 0, stream>>>(whT, wxT, xbf, bfp, bbp,
                                                       hr, hw, cst, out, s);
    }
  }
}

// Round 7
// 4450.710 us; speedup vs baseline: 1.8859x; 1.2802x over previous
//
#include <hip/hip_runtime.h>
#include <stdint.h>

#define B_ 64
#define T_ 512
#define D_ 1024
#define U_ 1024
#define G4_ 4096
#define M_ (B_ * T_)  // 32768

typedef unsigned short u16;
typedef float f32x4 __attribute__((ext_vector_type(4)));
typedef _Float16 f16x8 __attribute__((ext_vector_type(8)));
typedef unsigned short u16x4 __attribute__((ext_vector_type(4)));

__device__ __forceinline__ u16 f2h(float f) {
  union { _Float16 h; u16 u; } v; v.h = (_Float16)f; return v.u;
}
__device__ __forceinline__ float h2f(u16 u) {
  union { _Float16 h; u16 u; } v; v.u = u; return (float)v.h;
}
__device__ __forceinline__ float sigm(float x) { return 1.f / (1.f + __expf(-x)); }
__device__ __forceinline__ float tanhf_(float x) {
  x = fminf(12.f, fmaxf(-12.f, x));
  float e = __expf(2.f * x);
  return (e - 1.f) / (e + 1.f);
}

__device__ __forceinline__ void glds16(const void* g, void* l) {
  __builtin_amdgcn_global_load_lds(
      (const __attribute__((address_space(1))) uint32_t*)g,
      (__attribute__((address_space(3))) uint32_t*)l, 16, 0, 0);
}

// ---- generic row-strided stager: swizzle (row&7)<<4 applied to GLOBAL source
// (rule #21), LDS linear; read_frag applies the same XOR.
template <int R>
__device__ __forceinline__ void stage_tile(const char* gbase, long gs, char* lds, int tid) {
  const int lane = tid & 63, wid = tid >> 6;
#pragma unroll
  for (int j = wid; j < R / 8; j += 4) {  // each wave-instr covers 1KB = 8 rows
    const int row = j * 8 + (lane >> 3);
    const int lg = ((lane & 7) * 16) ^ ((row & 7) << 4);
    glds16(gbase + (long)row * gs + lg, lds + j * 1024);
  }
}

__device__ __forceinline__ f16x8 read_frag(const char* lds, int row, int kbyte) {
  const int ph = row * 128 + (kbyte ^ ((row & 7) << 4));
  return *(const f16x8*)(lds + ph);
}

#define MFMA_(a, b, c) __builtin_amdgcn_mfma_f32_16x16x32_f16(a, b, c, 0, 0, 0)

// raw barrier without VMEM drain (LDS ordering only)
#define BAR_LGKM() asm volatile("s_waitcnt lgkmcnt(0)\n\ts_barrier" ::: "memory")

// ---------------- prep kernels ----------------

__global__ __launch_bounds__(256) void cast_x_kernel(const float* __restrict__ x,
                                                     u16* __restrict__ xb) {
  const long n = (long)M_ * D_ / 4;
  for (long i = (long)blockIdx.x * blockDim.x + threadIdx.x; i < n;
       i += (long)gridDim.x * blockDim.x) {
    f32x4 v = ((const f32x4*)x)[i];
    u16x4 r;
#pragma unroll
    for (int j = 0; j < 4; ++j) r[j] = f2h(v[j]);
    ((u16x4*)xb)[i] = r;
  }
}

// Packed column p = ub*64 + g*16 + ui  <->  original col = g*1024 + ub*16 + ui.
__global__ __launch_bounds__(256) void pack_w_kernel(const float* __restrict__ Wf,
                                                     const float* __restrict__ Wb,
                                                     u16* __restrict__ wxT,
                                                     u16* __restrict__ whT) {
  const int idx = blockIdx.x * 256 + threadIdx.x;
  const int p = idx & 4095;
  const int kc = (idx >> 12) & 63;
  const int part = (idx >> 18) & 1;
  const int d = (idx >> 19) & 1;
  const float* W = d ? Wb : Wf;
  const int orig = ((p >> 4) & 3) * 1024 + ((p >> 6) << 4) + (p & 15);
  u16* dst = (part ? whT : wxT) + ((long)d * G4_ + p) * 1024 + kc * 16;
  const float* src = W + ((long)(part * 1024 + kc * 16)) * G4_ + orig;
#pragma unroll
  for (int j = 0; j < 16; ++j) dst[j] = f2h(src[(long)j * G4_]);
}

// ---------------- big x-projection GEMM (128x128 tile) ----------------
// Writes xp2 layout [d][t][ub(64)][b(64)][pl(64)] fp16, bias folded in.
__global__ __launch_bounds__(256) void gemm_xproj2(const u16* __restrict__ xbf,
                                                   const u16* __restrict__ wT,
                                                   const float* __restrict__ bF,
                                                   const float* __restrict__ bB,
                                                   u16* __restrict__ xp2) {
  __shared__ __align__(16) char smem[64 * 1024];
  const int tid = threadIdx.x, lane = tid & 63, wid = tid >> 6;
  const int wr = wid >> 1, wc = wid & 1;
  const int tm = blockIdx.x * 128, tn = blockIdx.y * 128, d = blockIdx.z;
  const char* Ag = (const char*)xbf + (long)tm * 2048;
  const char* Bg = (const char*)wT + ((long)d * G4_ + tn) * 2048;

  f32x4 acc[4][4];
#pragma unroll
  for (int mi = 0; mi < 4; ++mi)
#pragma unroll
    for (int ni = 0; ni < 4; ++ni)
#pragma unroll
      for (int v = 0; v < 4; ++v) acc[mi][ni][v] = 0.f;

  stage_tile<128>(Ag, 2048, smem, tid);
  stage_tile<128>(Bg, 2048, smem + 32768, tid);
  __syncthreads();
  const int rA = lane & 15, kb = (lane >> 4) * 16;

  for (int cc = 0; cc < 16; ++cc) {
    const int cur = cc & 1;
    char* Ac = smem + cur * 16384;
    char* Bc = smem + 32768 + cur * 16384;
    if (cc + 1 < 16) {
      stage_tile<128>(Ag + (cc + 1) * 128, 2048, smem + (cur ^ 1) * 16384, tid);
      stage_tile<128>(Bg + (cc + 1) * 128, 2048, smem + 32768 + (cur ^ 1) * 16384, tid);
    }
    f16x8 aF[4][2], bFr[4][2];
#pragma unroll
    for (int mi = 0; mi < 4; ++mi)
#pragma unroll
      for (int ks = 0; ks < 2; ++ks)
        aF[mi][ks] = read_frag(Ac, wr * 64 + mi * 16 + rA, kb + ks * 64);
#pragma unroll
    for (int ni = 0; ni < 4; ++ni)
#pragma unroll
      for (int ks = 0; ks < 2; ++ks)
        bFr[ni][ks] = read_frag(Bc, wc * 64 + ni * 16 + rA, kb + ks * 64);
#pragma unroll
    for (int mi = 0; mi < 4; ++mi)
#pragma unroll
      for (int ni = 0; ni < 4; ++ni)
#pragma unroll
        for (int ks = 0; ks < 2; ++ks)
          acc[mi][ni] = MFMA_(aF[mi][ks], bFr[ni][ks], acc[mi][ni]);
    __syncthreads();
  }

  const float* bias = d ? bB : bF;
#pragma unroll
  for (int ni = 0; ni < 4; ++ni) {
    const int p = tn + wc * 64 + ni * 16 + rA;
    const int orig = ((p >> 4) & 3) * 1024 + ((p >> 6) << 4) + (p & 15);
    const float bv = bias[orig];
    const int ub2 = p >> 6, pl = p & 63;
#pragma unroll
    for (int mi = 0; mi < 4; ++mi) {
      const int m0 = tm + wr * 64 + mi * 16 + (lane >> 4) * 4;
#pragma unroll
      for (int v = 0; v < 4; ++v) {
        const int m = m0 + v, b = m >> 9, t = m & 511;
        xp2[((((long)d * T_ + t) * 64 + ub2) * 64 + b) * 64 + pl] =
            f2h(acc[mi][ni][v] + bv);
      }
    }
  }
}

// ---------------- persistent recurrent kernel v3 ----------------
// 128 blocks (d, ub), 512 threads, 8 waves = 4 M-groups x 2 K-halves.
// Wh slice (64 cols x 1024 K) LDS-resident. Hand-rolled ordering:
//   - barriers are lgkm-only (never drain VMEM)
//   - A (h) via sc0/sc1 LLC-direct loads; ONE counted vmcnt(4)
//   - xp via cached loads; vmcnt(0) just before gates
//   - h store sc0/sc1 -> per-wave vmcnt(0) -> barrier -> relaxed flag store
//     (hand-rolled release: no L2 writeback fence)
//   - out store issued after the flag, ack absorbed by next counted wait
__global__ __launch_bounds__(512) void lstm_persist(
    const u16* __restrict__ whT, const u16* __restrict__ xp2,
    u16* __restrict__ hst, float* __restrict__ out, uint32_t* flags) {
  __shared__ __align__(16) char smem[147456];  // W 128K | zbuf 16K
  float* zbuf = (float*)(smem + 131072);
  const int tid = threadIdx.x, lane = tid & 63, wid = tid >> 6;
  const int bx = blockIdx.x, d = bx & 1, ub = bx >> 1;
  const int wm = wid & 3, kh = wid >> 2, rA = lane & 15, kq = lane >> 4;

  // ---- stage weights once (src-XOR swizzled, LDS linear; rule #21) ----
  {
    const char* wbase = (const char*)(whT + ((long)d * G4_ + ub * 64) * 1024);
#pragma unroll
    for (int q = 0; q < 16; ++q) {
      const int idx = wid * 16 + q;               // 128 x 1KB
      const int row = idx >> 1;                   // packed col 0..63
      const int jl = (idx & 1) * 1024 + lane * 16;
      glds16(wbase + (long)row * 2048 + (jl ^ ((row & 7) << 4)), smem + idx * 1024);
    }
  }
  // weights must land before first MFMA (barriers below don't drain VMEM)
  asm volatile("s_waitcnt vmcnt(0)" ::: "memory");
  __syncthreads();

  // gate-phase mapping: thread -> b = tid>>3, u-pair up = tid&7 (2 adjacent u)
  const int b_g = tid >> 3, up_g = tid & 7;
  const int u_g = ub * 16 + up_g * 2;
  float creg0 = 0.f, creg1 = 0.f;
  uint32_t* fl = flags + (long)d * 64 * 4;  // 16B-padded slots

  for (int s = 0; s < T_; ++s) {
    const int t = d ? (T_ - 1 - s) : s;

    // ---- barrier: all 64 blocks of this dir finished step s-1 ----
    if (wid == 0) {
      const uint32_t* fp = fl + lane * 4;
      int it = 0;
      while (true) {
        uint32_t v;
        asm volatile("global_load_dword %0, %1, off sc0 sc1\n\ts_waitcnt vmcnt(0)"
                     : "=v"(v) : "v"(fp) : "memory");
        if (__all(v >= (uint32_t)s)) break;
        __builtin_amdgcn_s_sleep(1);
        if (++it > (1 << 17)) break;  // bailout: terminate rather than hang
      }
    }
    BAR_LGKM();  // B1: release waves; no VMEM drain

    // ---- A-loads: 16 x dwordx4 sc0 sc1 (LLC-direct), then 4 xp dwords ----
    const u16* hr = hst + (long)(s & 1) * 131072 + d * 65536;
    const char* abase =
        (const char*)(hr + ((long)(wm * 16 + rA)) * 1024) + kh * 1024 + kq * 16;
    f16x8 areg[16];
#define ALOAD(i)                                                        \
  asm volatile("global_load_dwordx4 %0, %1, off offset:%2 sc0 sc1"     \
               : "=v"(areg[i]) : "v"(abase), "n"(i * 64) : "memory")
    ALOAD(0); ALOAD(1); ALOAD(2); ALOAD(3);
    ALOAD(4); ALOAD(5); ALOAD(6); ALOAD(7);
    ALOAD(8); ALOAD(9); ALOAD(10); ALOAD(11);
    ALOAD(12); ALOAD(13); ALOAD(14); ALOAD(15);
#undef ALOAD
    const u16* xb0 = xp2 + ((((long)d * T_ + t) * 64 + ub) * 64 + b_g) * 64 + up_g * 2;
    uint32_t xr[4];
#define XLOAD(g)                                                        \
  asm volatile("global_load_dword %0, %1, off offset:%2"               \
               : "=v"(xr[g]) : "v"(xb0), "n"(g * 32) : "memory")
    XLOAD(0); XLOAD(1); XLOAD(2); XLOAD(3);
#undef XLOAD
    // wait for A only (leaves the 4 xp loads in flight)
    asm volatile("s_waitcnt vmcnt(4)" ::: "memory");
    __builtin_amdgcn_sched_barrier(0);  // rule #18

    // ---- MFMA burst: rows wm*16..+15, all 64 cols, K-half kh ----
    f32x4 acc[4];
#pragma unroll
    for (int ni = 0; ni < 4; ++ni)
#pragma unroll
      for (int v = 0; v < 4; ++v) acc[ni][v] = 0.f;
#pragma unroll
    for (int kk = 0; kk < 16; ++kk) {
      const int kbyte = kh * 1024 + kk * 64 + kq * 16;
#pragma unroll
      for (int ni = 0; ni < 4; ++ni) {
        const int pi = ni * 16 + rA;
        const f16x8 bF =
            *(const f16x8*)(smem + pi * 2048 + (kbyte ^ ((pi & 7) << 4)));
        acc[ni] = MFMA_(areg[kk], bF, acc[ni]);
      }
    }

    // ---- K-combine via zbuf: kh1 writes, kh0 adds (lgkm-only barriers) ----
    if (kh == 1) {
#pragma unroll
      for (int ni = 0; ni < 4; ++ni)
#pragma unroll
        for (int v = 0; v < 4; ++v)
          zbuf[(wm * 16 + kq * 4 + v) * 64 + ni * 16 + rA] = acc[ni][v];
    }
    BAR_LGKM();  // B2
    if (kh == 0) {
#pragma unroll
      for (int ni = 0; ni < 4; ++ni)
#pragma unroll
        for (int v = 0; v < 4; ++v) {
          const int ix = (wm * 16 + kq * 4 + v) * 64 + ni * 16 + rA;
          zbuf[ix] += acc[ni][v];
        }
    }
    BAR_LGKM();  // B3

    // xp loads complete (only VMEM still outstanding for this wave)
    asm volatile("s_waitcnt vmcnt(0)" ::: "memory");
    __builtin_amdgcn_sched_barrier(0);

    // ---- gates: 2 adjacent units of one batch per thread ----
    const float* zb = zbuf + b_g * 64 + up_g * 2;
    const float zi0 = zb[0]  + h2f((u16)(xr[0] & 0xffff));
    const float zi1 = zb[1]  + h2f((u16)(xr[0] >> 16));
    const float zf0 = zb[16] + h2f((u16)(xr[1] & 0xffff));
    const float zf1 = zb[17] + h2f((u16)(xr[1] >> 16));
    const float zo0 = zb[32] + h2f((u16)(xr[2] & 0xffff));
    const float zo1 = zb[33] + h2f((u16)(xr[2] >> 16));
    const float zg0 = zb[48] + h2f((u16)(xr[3] & 0xffff));
    const float zg1 = zb[49] + h2f((u16)(xr[3] >> 16));
    const float cn0 = sigm(zf0) * creg0 + sigm(zi0) * tanhf_(zg0);
    const float cn1 = sigm(zf1) * creg1 + sigm(zi1) * tanhf_(zg1);
    const float hn0 = sigm(zo0) * tanhf_(cn0);
    const float hn1 = sigm(zo1) * tanhf_(cn1);
    creg0 = cn0; creg1 = cn1;

    // ---- h store (LLC write-through) -> ack -> barrier -> flag ----
    u16* hw = hst + (long)((s + 1) & 1) * 131072 + d * 65536;
    const uint32_t hv = (uint32_t)f2h(hn0) | ((uint32_t)f2h(hn1) << 16);
    u16* hptr = hw + (long)b_g * 1024 + u_g;
    asm volatile("global_store_dword %0, %1, off sc0 sc1"
                 :: "v"(hptr), "v"(hv) : "memory");
    asm volatile("s_waitcnt vmcnt(0)" ::: "memory");  // h ack'd (only h in flight)
    BAR_LGKM();  // B4: all threads' h stores ack'd
    if (tid == 0) {
      const uint32_t fv = (uint32_t)(s + 1);
      uint32_t* fp2 = fl + ub * 4;
      asm volatile("global_store_dword %0, %1, off sc0 sc1"
                   :: "v"(fp2), "v"(fv) : "memory");
    }

    // ---- out store AFTER release (ack absorbed by next counted wait) ----
    float2 o2; o2.x = hn0; o2.y = hn1;
    *(float2*)(out + ((long)b_g * T_ + t) * 2048 + d * 1024 + u_g) = o2;
  }
}

// ---------------- fused fallback (small workspace): r3-proven structure ------
__global__ __launch_bounds__(256) void lstm_step_fused(
    const u16* __restrict__ whT, const u16* __restrict__ wxT,
    const u16* __restrict__ xbf,
    const float* __restrict__ bF, const float* __restrict__ bB,
    const u16* __restrict__ h_read, u16* __restrict__ h_write,
    float* __restrict__ c_state, float* __restrict__ out, int s) {
  __shared__ __align__(16) char smem[32 * 1024];
  float* zbuf = (float*)smem;
  const int tid = threadIdx.x, lane = tid & 63, wid = tid >> 6;
  const int wr = wid >> 1, wc = wid & 1;
  const int ub = blockIdx.x, d = blockIdx.y;
  const int t = d ? (T_ - 1 - s) : s;
  const char* hA = (const char*)(h_read + (long)d * B_ * U_);
  const char* Bh = (const char*)(whT + ((long)d * G4_ + ub * 64) * 1024);
  const char* xA = (const char*)xbf + (long)t * (D_ * 2);
  const char* Bx = (const char*)(wxT + ((long)d * G4_ + ub * 64) * 1024);

  auto stage = [&](int cc, int buf) {
    char* Ad = smem + buf * 8192;
    char* Bd = smem + 16384 + buf * 8192;
    if (cc < 16) {
      stage_tile<64>(hA + cc * 128, U_ * 2, Ad, tid);
      stage_tile<64>(Bh + cc * 128, 1024 * 2, Bd, tid);
    } else {
      const int cx = cc - 16;
      stage_tile<64>(xA + cx * 128, (long)T_ * D_ * 2, Ad, tid);
      stage_tile<64>(Bx + cx * 128, 1024 * 2, Bd, tid);
    }
  };

  f32x4 acc[2][2];
#pragma unroll
  for (int mi = 0; mi < 2; ++mi)
#pragma unroll
    for (int ni = 0; ni < 2; ++ni)
#pragma unroll
      for (int v = 0; v < 4; ++v) acc[mi][ni][v] = 0.f;

  stage(0, 0);
  __syncthreads();
  const int rA = lane & 15, kb = (lane >> 4) * 16;

  for (int cc = 0; cc < 32; ++cc) {
    const int cur = cc & 1;
    char* Ac = smem + cur * 8192;
    char* Bc = smem + 16384 + cur * 8192;
    if (cc + 1 < 32) stage(cc + 1, cur ^ 1);
    f16x8 aF[2][2], bFr[2][2];
#pragma unroll
    for (int mi = 0; mi < 2; ++mi)
#pragma unroll
      for (int ks = 0; ks < 2; ++ks)
        aF[mi][ks] = read_frag(Ac, wr * 32 + mi * 16 + rA, kb + ks * 64);
#pragma unroll
    for (int ni = 0; ni < 2; ++ni)
#pragma unroll
      for (int ks = 0; ks < 2; ++ks)
        bFr[ni][ks] = read_frag(Bc, wc * 32 + ni * 16 + rA, kb + ks * 64);
#pragma unroll
    for (int mi = 0; mi < 2; ++mi)
#pragma unroll
      for (int ni = 0; ni < 2; ++ni)
#pragma unroll
        for (int ks = 0; ks < 2; ++ks)
          acc[mi][ni] = MFMA_(aF[mi][ks], bFr[ni][ks], acc[mi][ni]);
    __syncthreads();
  }

#pragma unroll
  for (int mi = 0; mi < 2; ++mi)
#pragma unroll
    for (int ni = 0; ni < 2; ++ni)
#pragma unroll
      for (int v = 0; v < 4; ++v) {
        const int row = wr * 32 + mi * 16 + (lane >> 4) * 4 + v;
        const int col = wc * 32 + ni * 16 + rA;
        zbuf[row * 64 + col] = acc[mi][ni][v];
      }
  __syncthreads();

  const int b = tid >> 2, u0 = (tid & 3) * 4;
  const float* bias = d ? bB : bF;
#pragma unroll
  for (int j = 0; j < 4; ++j) {
    const int ui = u0 + j, u = ub * 16 + ui;
    float zi = zbuf[b * 64 + ui] + bias[u];
    float zf = zbuf[b * 64 + 16 + ui] + bias[1024 + u];
    float zo = zbuf[b * 64 + 32 + ui] + bias[2048 + u];
    float zg = zbuf[b * 64 + 48 + ui] + bias[3072 + u];
    const long ci = (((long)d * B_ + b) << 10) + u;
    const float c = c_state[ci];
    const float i_ = sigm(zi), ff = sigm(zf), o_ = sigm(zo), g_ = tanhf_(zg);
    const float cn = ff * c + i_ * g_;
    const float hn = o_ * tanhf_(cn);
    c_state[ci] = cn;
    h_write[ci] = f2h(hn);
    out[(((long)b * T_ + t) << 11) + ((long)d << 10) + u] = hn;
  }
}

// ---------------- host launch ----------------

extern "C" void kernel_launch(void* const* d_in, const int* in_sizes, int n_in,
                              void* d_out, int out_size, void* d_ws, size_t ws_size,
                              hipStream_t stream) {
  const float* x = (const float*)d_in[0];
  const float* Wf = (const float*)d_in[1];
  const float* bfp = (const float*)d_in[2];
  const float* Wb = (const float*)d_in[3];
  const float* bbp = (const float*)d_in[4];
  float* out = (float*)d_out;
  char* ws = (char*)d_ws;

  size_t off = 0;
  auto alloc = [&](size_t bytes) {
    char* p = ws + off;
    off = (off + bytes + 255) & ~(size_t)255;
    return p;
  };
  u16* xbf = (u16*)alloc((size_t)M_ * D_ * 2);            // 64 MB
  u16* wxT = (u16*)alloc((size_t)2 * G4_ * 1024 * 2);     // 16 MB
  u16* whT = (u16*)alloc((size_t)2 * G4_ * 1024 * 2);     // 16 MB
  u16* hst = (u16*)alloc((size_t)2 * 2 * B_ * U_ * 2);    // ping-pong h
  float* cst = (float*)alloc((size_t)2 * B_ * U_ * 4);    // cell state (fallback)
  uint32_t* flags = (uint32_t*)alloc((size_t)2 * 64 * 16 * 4);  // barrier flags
  const size_t base_need = off;
  const size_t xproj_bytes = (size_t)2 * B_ * T_ * G4_ * 2;  // 512 MB
  const bool fused = (ws_size < base_need + xproj_bytes + 256);
  u16* xproj = fused ? nullptr : (u16*)alloc(xproj_bytes);

  hipMemsetAsync(hst, 0, (size_t)2 * 2 * B_ * U_ * 2, stream);
  hipMemsetAsync(flags, 0, (size_t)2 * 64 * 16 * 4, stream);

  cast_x_kernel<<<2048, 256, 0, stream>>>(x, xbf);
  pack_w_kernel<<<4096, 256, 0, stream>>>(Wf, Wb, wxT, whT);

  if (!fused) {
    dim3 gg(M_ / 128, G4_ / 128, 2);
    gemm_xproj2<<<gg, 256, 0, stream>>>(xbf, wxT, bfp, bbp, xproj);
    lstm_persist<<<128, 512, 0, stream>>>(whT, xproj, hst, out, flags);
  } else {
    hipMemsetAsync(cst, 0, (size_t)2 * B_ * U_ * 4, stream);
    for (int s = 0; s < T_; ++s) {
      const u16* hr = hst + (size_t)(s & 1) * 2 * B_ * U_;
      u16* hw = hst + (size_t)((s + 1) & 1) * 2 * B_ * U_;
      lstm_step_fused<<<dim3(64, 2), 256, 0, stream>>>(whT, wxT, xbf, bfp, bbp,
                                                       hr, hw, cst, out, s);
    }
  }
}